// Round 3
// baseline (1125.852 us; speedup 1.0000x reference)
//
#include <hip/hip_runtime.h>
#include <math.h>

// Problem constants (match reference setup_inputs)
#define NB 4
#define LQ 13294
#define LEN 13294
#define CCH 256
#define MH 8
#define LL 4
#define PP 4
#define DD 32
#define RTOT (NB * LQ)        // 53176 rows
#define NGRP (RTOT * MH)      // 425408 (n,q,m) groups

// ---------------------------------------------------------------------------
// fp32 GEMM: C[r, c] = sum_k A[r,k] * B[k,c] + bias[c]
// A: (Rrows, K) row-major, B: (K, Nc) row-major.
// BM=BN=64, BK=16, 256 threads, each thread 4x4 micro-tile.
// ---------------------------------------------------------------------------
__global__ __launch_bounds__(256) void gemm_bias_kernel(
    const float* __restrict__ A, const float* __restrict__ Bm,
    const float* __restrict__ bias, float* __restrict__ Cm,
    int Rrows, int K, int Nc)
{
    constexpr int BM = 64, BN = 64, BK = 16;
    __shared__ float As[BK][BM + 4];   // A transposed in LDS, padded
    __shared__ float Bs[BK][BN];

    const int t  = threadIdx.x;
    const int tx = t & 15;
    const int ty = t >> 4;
    const int blockRow = blockIdx.x * BM;
    const int blockCol = blockIdx.y * BN;

    float acc[4][4] = {};

    // A staging: thread loads one float4: row = t>>2 (0..63), kcol = (t&3)*4
    const int ar = t >> 2;
    const int ak = (t & 3) * 4;
    // B staging: row = t>>4 (0..15), col = (t&15)*4
    const int br = t >> 4;
    const int bc = (t & 15) * 4;

    const int  gar  = blockRow + ar;
    const bool aval = (gar < Rrows);
    const float* Aptr = A + (size_t)(aval ? gar : 0) * K + ak;
    const float* Bptr = Bm + (size_t)br * Nc + blockCol + bc;

    for (int k0 = 0; k0 < K; k0 += BK) {
        float4 av = aval ? *(const float4*)Aptr : make_float4(0.f, 0.f, 0.f, 0.f);
        float4 bv = *(const float4*)Bptr;
        __syncthreads();
        As[ak + 0][ar] = av.x;
        As[ak + 1][ar] = av.y;
        As[ak + 2][ar] = av.z;
        As[ak + 3][ar] = av.w;
        *(float4*)&Bs[br][bc] = bv;
        __syncthreads();
#pragma unroll
        for (int kk = 0; kk < BK; ++kk) {
            float4 a = *(const float4*)&As[kk][ty * 4];
            float4 b = *(const float4*)&Bs[kk][tx * 4];
            acc[0][0] = fmaf(a.x, b.x, acc[0][0]);
            acc[0][1] = fmaf(a.x, b.y, acc[0][1]);
            acc[0][2] = fmaf(a.x, b.z, acc[0][2]);
            acc[0][3] = fmaf(a.x, b.w, acc[0][3]);
            acc[1][0] = fmaf(a.y, b.x, acc[1][0]);
            acc[1][1] = fmaf(a.y, b.y, acc[1][1]);
            acc[1][2] = fmaf(a.y, b.z, acc[1][2]);
            acc[1][3] = fmaf(a.y, b.w, acc[1][3]);
            acc[2][0] = fmaf(a.z, b.x, acc[2][0]);
            acc[2][1] = fmaf(a.z, b.y, acc[2][1]);
            acc[2][2] = fmaf(a.z, b.z, acc[2][2]);
            acc[2][3] = fmaf(a.z, b.w, acc[2][3]);
            acc[3][0] = fmaf(a.w, b.x, acc[3][0]);
            acc[3][1] = fmaf(a.w, b.y, acc[3][1]);
            acc[3][2] = fmaf(a.w, b.z, acc[3][2]);
            acc[3][3] = fmaf(a.w, b.w, acc[3][3]);
        }
        Aptr += BK;
        Bptr += (size_t)BK * Nc;
    }

#pragma unroll
    for (int i = 0; i < 4; ++i) {
        int r = blockRow + ty * 4 + i;
        if (r < Rrows) {
#pragma unroll
            for (int j = 0; j < 4; ++j) {
                int c = blockCol + tx * 4 + j;
                Cm[(size_t)r * Nc + c] = acc[i][j] + bias[c];
            }
        }
    }
}

// ---------------------------------------------------------------------------
// Softmax over groups of 16 contiguous floats (per n,q,m) — in place.
// ---------------------------------------------------------------------------
__global__ __launch_bounds__(256) void softmax16_kernel(float* __restrict__ aw)
{
    int g = blockIdx.x * 256 + threadIdx.x;
    if (g >= NGRP) return;
    float4* p = (float4*)(aw + (size_t)g * 16);
    float4 v0 = p[0], v1 = p[1], v2 = p[2], v3 = p[3];
    float vals[16] = { v0.x, v0.y, v0.z, v0.w, v1.x, v1.y, v1.z, v1.w,
                       v2.x, v2.y, v2.z, v2.w, v3.x, v3.y, v3.z, v3.w };
    float mx = vals[0];
#pragma unroll
    for (int i = 1; i < 16; ++i) mx = fmaxf(mx, vals[i]);
    float s = 0.f;
#pragma unroll
    for (int i = 0; i < 16; ++i) { vals[i] = expf(vals[i] - mx); s += vals[i]; }
    float inv = 1.f / s;
#pragma unroll
    for (int i = 0; i < 16; ++i) vals[i] *= inv;
    p[0] = make_float4(vals[0], vals[1], vals[2], vals[3]);
    p[1] = make_float4(vals[4], vals[5], vals[6], vals[7]);
    p[2] = make_float4(vals[8], vals[9], vals[10], vals[11]);
    p[3] = make_float4(vals[12], vals[13], vals[14], vals[15]);
}

// ---------------------------------------------------------------------------
// Bilinear sampling + attention-weighted accumulation.
// One 32-lane group per (n,q,m); lane = channel d. 8 groups / 256-thr block.
// value: (N*LEN, 256) row-major, col = m*32 + d
// off:   (N*LQ, 256)  col = m*32 + (l*4+p)*2 + {x,y}
// aw:    (N*LQ, 128)  col = m*16 + l*4 + p   (softmaxed)
// refp:  (N*LQ, 4, 2)
// samp:  (N*LQ, 256)  col = m*32 + d
// ---------------------------------------------------------------------------
__global__ __launch_bounds__(256) void sample_kernel(
    const float* __restrict__ value, const float* __restrict__ off,
    const float* __restrict__ aw, const float* __restrict__ refp,
    const int* __restrict__ shapes, const int* __restrict__ starts,
    float* __restrict__ samp)
{
    int grp = blockIdx.x * 8 + (threadIdx.x >> 5);
    if (grp >= NGRP) return;
    const int d   = threadIdx.x & 31;
    const int m   = grp & (MH - 1);
    const int row = grp >> 3;             // n*LQ + q
    const int n   = row / LQ;

    const float* offp = off + (size_t)row * 256 + m * 32;
    const float* awp  = aw + (size_t)row * 128 + m * 16;
    const float* vbase = value + (size_t)n * LEN * 256 + m * 32 + d;

    float acc = 0.f;
#pragma unroll
    for (int l = 0; l < LL; ++l) {
        const int H = shapes[2 * l];
        const int W = shapes[2 * l + 1];
        const int st = starts[l];
        const float rx = refp[((size_t)row * 4 + l) * 2 + 0];
        const float ry = refp[((size_t)row * 4 + l) * 2 + 1];
        const float fW = (float)W, fH = (float)H;
        const float* vl = vbase + (size_t)st * 256;
#pragma unroll
        for (int p = 0; p < PP; ++p) {
            const float ox = offp[(l * 4 + p) * 2 + 0];
            const float oy = offp[(l * 4 + p) * 2 + 1];
            const float wa = awp[l * 4 + p];
            const float x = fmaf(rx, fW, ox) - 0.5f;   // (rx + ox/W)*W - 0.5
            const float y = fmaf(ry, fH, oy) - 0.5f;
            const float x0f = floorf(x), y0f = floorf(y);
            const float wx = x - x0f, wy = y - y0f;
            const int x0 = (int)x0f, y0 = (int)y0f;
            const int x1 = x0 + 1, y1 = y0 + 1;
            const bool vx0 = (x0 >= 0) & (x0 < W);
            const bool vx1 = (x1 >= 0) & (x1 < W);
            const bool vy0 = (y0 >= 0) & (y0 < H);
            const bool vy1 = (y1 >= 0) & (y1 < H);
            float s = 0.f;
            if (vy0) {
                const float* rowp = vl + (size_t)(y0 * W) * 256;
                if (vx0) s = fmaf((1.f - wx) * (1.f - wy), rowp[(size_t)x0 * 256], s);
                if (vx1) s = fmaf(wx * (1.f - wy),         rowp[(size_t)x1 * 256], s);
            }
            if (vy1) {
                const float* rowp = vl + (size_t)(y1 * W) * 256;
                if (vx0) s = fmaf((1.f - wx) * wy, rowp[(size_t)x0 * 256], s);
                if (vx1) s = fmaf(wx * wy,         rowp[(size_t)x1 * 256], s);
            }
            acc = fmaf(wa, s, acc);
        }
    }
    samp[(size_t)row * 256 + m * 32 + d] = acc;
}

// ---------------------------------------------------------------------------
extern "C" void kernel_launch(void* const* d_in, const int* in_sizes, int n_in,
                              void* d_out, int out_size, void* d_ws, size_t ws_size,
                              hipStream_t stream)
{
    const float* query  = (const float*)d_in[0];
    const float* refp   = (const float*)d_in[1];
    const float* inp    = (const float*)d_in[2];
    const int*   shapes = (const int*)d_in[3];
    const int*   starts = (const int*)d_in[4];
    const float* Wv     = (const float*)d_in[5];
    const float* bv     = (const float*)d_in[6];
    const float* W_off  = (const float*)d_in[7];
    const float* b_off  = (const float*)d_in[8];
    const float* W_attn = (const float*)d_in[9];
    const float* b_attn = (const float*)d_in[10];
    const float* Wo     = (const float*)d_in[11];
    const float* bo     = (const float*)d_in[12];
    float* out = (float*)d_out;

    float* ws    = (float*)d_ws;
    float* value = ws;                                   // RTOT*256
    float* off   = value + (size_t)RTOT * 256;           // RTOT*256
    float* aw    = off + (size_t)RTOT * 256;             // RTOT*128
    float* samp  = aw + (size_t)RTOT * 128;              // RTOT*256

    dim3 blk(256);
    dim3 gFull((RTOT + 63) / 64, CCH / 64);   // (831, 4)
    dim3 gHalf((RTOT + 63) / 64, 128 / 64);   // (831, 2)

    // value projection
    gemm_bias_kernel<<<gFull, blk, 0, stream>>>(inp, Wv, bv, value, RTOT, CCH, CCH);
    // sampling offsets
    gemm_bias_kernel<<<gFull, blk, 0, stream>>>(query, W_off, b_off, off, RTOT, CCH, CCH);
    // attention logits
    gemm_bias_kernel<<<gHalf, blk, 0, stream>>>(query, W_attn, b_attn, aw, RTOT, CCH, 128);
    // softmax over L*P=16
    softmax16_kernel<<<(NGRP + 255) / 256, blk, 0, stream>>>(aw);
    // bilinear sampling + weighted sum
    sample_kernel<<<(NGRP + 7) / 8, blk, 0, stream>>>(value, off, aw, refp, shapes, starts, samp);
    // output projection
    gemm_bias_kernel<<<gFull, blk, 0, stream>>>(samp, Wo, bo, out, RTOT, CCH, CCH);
}

// Round 4
// 638.702 us; speedup vs baseline: 1.7627x; 1.7627x over previous
//
#include <hip/hip_runtime.h>
#include <math.h>

// Problem constants (match reference setup_inputs)
#define NB 4
#define LQ 13294
#define LEN 13294
#define CCH 256
#define MH 8
#define LL 4
#define PP 4
#define DD 32
#define RTOT (NB * LQ)        // 53176 rows
#define NGRP (RTOT * MH)      // 425408 (n,q,m) groups

// ---------------------------------------------------------------------------
// fp32 GEMM: C[r, c] = sum_k A[r,k] * B[k,c] + bias[c]
// A: (Rrows, K) row-major, B: (K, Nc) row-major.
// BM=BN=64, BK=16, 256 threads, each thread 4x4 micro-tile.
// ---------------------------------------------------------------------------
__global__ __launch_bounds__(256) void gemm_bias_kernel(
    const float* __restrict__ A, const float* __restrict__ Bm,
    const float* __restrict__ bias, float* __restrict__ Cm,
    int Rrows, int K, int Nc)
{
    constexpr int BM = 64, BN = 64, BK = 16;
    __shared__ float As[BK][BM + 4];   // A transposed in LDS, padded
    __shared__ float Bs[BK][BN];

    const int t  = threadIdx.x;
    const int tx = t & 15;
    const int ty = t >> 4;
    const int blockRow = blockIdx.x * BM;
    const int blockCol = blockIdx.y * BN;

    float acc[4][4] = {};

    // A staging: thread loads one float4: row = t>>2 (0..63), kcol = (t&3)*4
    const int ar = t >> 2;
    const int ak = (t & 3) * 4;
    // B staging: row = t>>4 (0..15), col = (t&15)*4
    const int br = t >> 4;
    const int bc = (t & 15) * 4;

    const int  gar  = blockRow + ar;
    const bool aval = (gar < Rrows);
    const float* Aptr = A + (size_t)(aval ? gar : 0) * K + ak;
    const float* Bptr = Bm + (size_t)br * Nc + blockCol + bc;

    for (int k0 = 0; k0 < K; k0 += BK) {
        float4 av = aval ? *(const float4*)Aptr : make_float4(0.f, 0.f, 0.f, 0.f);
        float4 bv = *(const float4*)Bptr;
        __syncthreads();
        As[ak + 0][ar] = av.x;
        As[ak + 1][ar] = av.y;
        As[ak + 2][ar] = av.z;
        As[ak + 3][ar] = av.w;
        *(float4*)&Bs[br][bc] = bv;
        __syncthreads();
#pragma unroll
        for (int kk = 0; kk < BK; ++kk) {
            float4 a = *(const float4*)&As[kk][ty * 4];
            float4 b = *(const float4*)&Bs[kk][tx * 4];
            acc[0][0] = fmaf(a.x, b.x, acc[0][0]);
            acc[0][1] = fmaf(a.x, b.y, acc[0][1]);
            acc[0][2] = fmaf(a.x, b.z, acc[0][2]);
            acc[0][3] = fmaf(a.x, b.w, acc[0][3]);
            acc[1][0] = fmaf(a.y, b.x, acc[1][0]);
            acc[1][1] = fmaf(a.y, b.y, acc[1][1]);
            acc[1][2] = fmaf(a.y, b.z, acc[1][2]);
            acc[1][3] = fmaf(a.y, b.w, acc[1][3]);
            acc[2][0] = fmaf(a.z, b.x, acc[2][0]);
            acc[2][1] = fmaf(a.z, b.y, acc[2][1]);
            acc[2][2] = fmaf(a.z, b.z, acc[2][2]);
            acc[2][3] = fmaf(a.z, b.w, acc[2][3]);
            acc[3][0] = fmaf(a.w, b.x, acc[3][0]);
            acc[3][1] = fmaf(a.w, b.y, acc[3][1]);
            acc[3][2] = fmaf(a.w, b.z, acc[3][2]);
            acc[3][3] = fmaf(a.w, b.w, acc[3][3]);
        }
        Aptr += BK;
        Bptr += (size_t)BK * Nc;
    }

#pragma unroll
    for (int i = 0; i < 4; ++i) {
        int r = blockRow + ty * 4 + i;
        if (r < Rrows) {
#pragma unroll
            for (int j = 0; j < 4; ++j) {
                int c = blockCol + tx * 4 + j;
                Cm[(size_t)r * Nc + c] = acc[i][j] + bias[c];
            }
        }
    }
}

// ---------------------------------------------------------------------------
// Softmax over groups of 16 contiguous floats (per n,q,m) — in place.
// ---------------------------------------------------------------------------
__global__ __launch_bounds__(256) void softmax16_kernel(float* __restrict__ aw)
{
    int g = blockIdx.x * 256 + threadIdx.x;
    if (g >= NGRP) return;
    float4* p = (float4*)(aw + (size_t)g * 16);
    float4 v0 = p[0], v1 = p[1], v2 = p[2], v3 = p[3];
    float vals[16] = { v0.x, v0.y, v0.z, v0.w, v1.x, v1.y, v1.z, v1.w,
                       v2.x, v2.y, v2.z, v2.w, v3.x, v3.y, v3.z, v3.w };
    float mx = vals[0];
#pragma unroll
    for (int i = 1; i < 16; ++i) mx = fmaxf(mx, vals[i]);
    float s = 0.f;
#pragma unroll
    for (int i = 0; i < 16; ++i) { vals[i] = expf(vals[i] - mx); s += vals[i]; }
    float inv = 1.f / s;
#pragma unroll
    for (int i = 0; i < 16; ++i) vals[i] *= inv;
    p[0] = make_float4(vals[0], vals[1], vals[2], vals[3]);
    p[1] = make_float4(vals[4], vals[5], vals[6], vals[7]);
    p[2] = make_float4(vals[8], vals[9], vals[10], vals[11]);
    p[3] = make_float4(vals[12], vals[13], vals[14], vals[15]);
}

// ---------------------------------------------------------------------------
// Bilinear sampling + attention-weighted accumulation — float4 / 8-lane groups.
//
// Group = (n,q,m). 8 lanes per group; lane l8 owns channels [4*l8, 4*l8+4)
// (one float4 gather per corner → wave of 64 lanes = 8 groups, 4x fewer
// waves than the 32-lane-scalar version) AND owns the coordinate math for
// points j = 2*l8, 2*l8+1 (matches the off float4 layout exactly:
// offv = {x(2l),y(2l),x(2l+1),y(2l+1)}). Corner indices (st folded in) and
// wa-folded bilinear weights (validity zeroed — identical to the reference's
// clip+mask semantics) are broadcast via __shfl(.., owner, 8). Branchless.
//
// value: (N*LEN, 256) row-major, col = m*32 + d
// off:   (N*LQ, 256)  col = m*32 + (l*4+p)*2 + {x,y}
// aw:    (N*LQ, 128)  col = m*16 + l*4 + p   (softmaxed)
// refp:  (N*LQ, 4, 2)
// samp:  (N*LQ, 256)  col = m*32 + d
// ---------------------------------------------------------------------------
__global__ __launch_bounds__(256) void sample_kernel(
    const float* __restrict__ value, const float* __restrict__ off,
    const float* __restrict__ aw, const float* __restrict__ refp,
    const int* __restrict__ shapes, const int* __restrict__ starts,
    float* __restrict__ samp)
{
    const int grp = blockIdx.x * 32 + (threadIdx.x >> 3);   // grid is exact: NGRP = 13294*32
    const int l8  = threadIdx.x & 7;
    const int m   = grp & (MH - 1);
    const int row = grp >> 3;             // n*LQ + q
    const int n   = row / LQ;

    // cooperative per-group loads (wave = 8 groups = one full contiguous row)
    const float4 offv = *(const float4*)(off + (size_t)row * 256 + m * 32 + l8 * 4);
    const float2 aw2  = *(const float2*)(aw  + (size_t)row * 128 + m * 16 + l8 * 2);

    // owner-side: points 2*l8, 2*l8+1, both in level l8>>1
    const int lvl = l8 >> 1;
    const int H  = shapes[2 * lvl];
    const int W  = shapes[2 * lvl + 1];
    const int st = starts[lvl];
    const float rx = refp[(size_t)row * 8 + lvl * 2 + 0];
    const float ry = refp[(size_t)row * 8 + lvl * 2 + 1];

    int   idx[2][4];
    float wgt[2][4];
#pragma unroll
    for (int s = 0; s < 2; ++s) {
        const float ox = s ? offv.z : offv.x;
        const float oy = s ? offv.w : offv.y;
        const float wa = s ? aw2.y  : aw2.x;
        const float x = fmaf(rx, (float)W, ox) - 0.5f;   // (rx + ox/W)*W - 0.5
        const float y = fmaf(ry, (float)H, oy) - 0.5f;
        const float x0f = floorf(x), y0f = floorf(y);
        const float wx = x - x0f, wy = y - y0f;
        const int x0 = (int)x0f, y0 = (int)y0f;
        const int x1 = x0 + 1,   y1 = y0 + 1;
        const float vx0 = (x0 >= 0 && x0 < W) ? 1.f : 0.f;
        const float vx1 = (x1 >= 0 && x1 < W) ? 1.f : 0.f;
        const float vy0 = (y0 >= 0 && y0 < H) ? 1.f : 0.f;
        const float vy1 = (y1 >= 0 && y1 < H) ? 1.f : 0.f;
        const int xc0 = min(max(x0, 0), W - 1);
        const int xc1 = min(max(x1, 0), W - 1);
        const int rb0 = min(max(y0, 0), H - 1) * W;
        const int rb1 = min(max(y1, 0), H - 1) * W;
        idx[s][0] = st + rb0 + xc0;
        idx[s][1] = st + rb0 + xc1;
        idx[s][2] = st + rb1 + xc0;
        idx[s][3] = st + rb1 + xc1;
        wgt[s][0] = (1.f - wx) * (1.f - wy) * vx0 * vy0 * wa;
        wgt[s][1] = wx * (1.f - wy) * vx1 * vy0 * wa;
        wgt[s][2] = (1.f - wx) * wy * vx0 * vy1 * wa;
        wgt[s][3] = wx * wy * vx1 * vy1 * wa;
    }

    const float* vb = value + (size_t)n * LEN * 256 + m * 32 + l8 * 4;

    float4 acc = make_float4(0.f, 0.f, 0.f, 0.f);
#pragma unroll
    for (int j = 0; j < 16; ++j) {
        const int owner = j >> 1;
        const int s     = j & 1;
#pragma unroll
        for (int c = 0; c < 4; ++c) {
            const int   ic = __shfl(idx[s][c], owner, 8);
            const float wc = __shfl(wgt[s][c], owner, 8);
            const float4 v = *(const float4*)(vb + ((size_t)ic << 8));
            acc.x = fmaf(wc, v.x, acc.x);
            acc.y = fmaf(wc, v.y, acc.y);
            acc.z = fmaf(wc, v.z, acc.z);
            acc.w = fmaf(wc, v.w, acc.w);
        }
    }
    *(float4*)(samp + (size_t)row * 256 + m * 32 + l8 * 4) = acc;
}

// ---------------------------------------------------------------------------
extern "C" void kernel_launch(void* const* d_in, const int* in_sizes, int n_in,
                              void* d_out, int out_size, void* d_ws, size_t ws_size,
                              hipStream_t stream)
{
    const float* query  = (const float*)d_in[0];
    const float* refp   = (const float*)d_in[1];
    const float* inp    = (const float*)d_in[2];
    const int*   shapes = (const int*)d_in[3];
    const int*   starts = (const int*)d_in[4];
    const float* Wv     = (const float*)d_in[5];
    const float* bv     = (const float*)d_in[6];
    const float* W_off  = (const float*)d_in[7];
    const float* b_off  = (const float*)d_in[8];
    const float* W_attn = (const float*)d_in[9];
    const float* b_attn = (const float*)d_in[10];
    const float* Wo     = (const float*)d_in[11];
    const float* bo     = (const float*)d_in[12];
    float* out = (float*)d_out;

    float* ws    = (float*)d_ws;
    float* value = ws;                                   // RTOT*256
    float* off   = value + (size_t)RTOT * 256;           // RTOT*256
    float* aw    = off + (size_t)RTOT * 256;             // RTOT*128
    float* samp  = aw + (size_t)RTOT * 128;              // RTOT*256

    dim3 blk(256);
    dim3 gFull((RTOT + 63) / 64, CCH / 64);   // (831, 4)
    dim3 gHalf((RTOT + 63) / 64, 128 / 64);   // (831, 2)

    // value projection
    gemm_bias_kernel<<<gFull, blk, 0, stream>>>(inp, Wv, bv, value, RTOT, CCH, CCH);
    // sampling offsets
    gemm_bias_kernel<<<gFull, blk, 0, stream>>>(query, W_off, b_off, off, RTOT, CCH, CCH);
    // attention logits
    gemm_bias_kernel<<<gHalf, blk, 0, stream>>>(query, W_attn, b_attn, aw, RTOT, CCH, 128);
    // softmax over L*P=16
    softmax16_kernel<<<(NGRP + 255) / 256, blk, 0, stream>>>(aw);
    // bilinear sampling + weighted sum (32 groups per block; grid exact)
    sample_kernel<<<NGRP / 32, blk, 0, stream>>>(value, off, aw, refp, shapes, starts, samp);
    // output projection
    gemm_bias_kernel<<<gFull, blk, 0, stream>>>(samp, Wo, bo, out, RTOT, CCH, CCH);
}

// Round 6
// 525.372 us; speedup vs baseline: 2.1430x; 1.2157x over previous
//
#include <hip/hip_runtime.h>
#include <math.h>

// Problem constants (match reference setup_inputs)
#define NB 4
#define LQ 13294
#define LEN 13294
#define CCH 256
#define MH 8
#define LL 4
#define PP 4
#define DD 32
#define RTOT (NB * LQ)        // 53176 rows
#define NGRP (RTOT * MH)      // 425408 (n,q,m) groups

typedef short bf16x8 __attribute__((ext_vector_type(8)));
typedef float f32x4  __attribute__((ext_vector_type(4)));

static __device__ __forceinline__ unsigned short f2bf(float f) {
    union { float f; unsigned int u; } v; v.f = f;
    unsigned int r = v.u + 0x7fffu + ((v.u >> 16) & 1u);   // RNE
    return (unsigned short)(r >> 16);
}

static __device__ __forceinline__ bf16x8 pack8(float4 a, float4 b) {
    bf16x8 r;
    r[0] = (short)f2bf(a.x); r[1] = (short)f2bf(a.y);
    r[2] = (short)f2bf(a.z); r[3] = (short)f2bf(a.w);
    r[4] = (short)f2bf(b.x); r[5] = (short)f2bf(b.y);
    r[6] = (short)f2bf(b.z); r[7] = (short)f2bf(b.w);
    return r;
}

// ---------------------------------------------------------------------------
// bf16-MFMA GEMM with bias: C[r,c] = sum_k A[r,k]*B[k,c] + bias[c]
// A: (Rrows, 256) fp32 row-major; B: (256, Nc) fp32 row-major. K = 256.
// BM=128, BN=64, BK=32. 256 threads = 4 waves in 2x2; per-wave 64x32 out.
// B fragments (whole K) preloaded to registers (16 frags = 64 VGPR/lane);
// A converted fp32->bf16 and staged in LDS [128][40] per K-step.
// MFMA 16x16x32_bf16; layouts per m89/m97-verified gemm_bt pattern.
// ---------------------------------------------------------------------------
__global__ __launch_bounds__(256) void gemm_mfma_bias(
    const float* __restrict__ A, const float* __restrict__ Bm,
    const float* __restrict__ bias, float* __restrict__ Cm,
    int Rrows, int Nc)
{
    __shared__ unsigned short As[128 * 40];   // [row][40], 32 used, pad 8 (2-way banks)

    const int t    = threadIdx.x;
    const int lane = t & 63;
    const int w    = t >> 6;
    const int wr   = w >> 1;        // 0..1 : row half
    const int wc   = w & 1;         // 0..1 : col half
    const int blockRow = blockIdx.y * 128;
    const int blockCol = blockIdx.x * 64;

    const int l16 = lane & 15;
    const int kg  = lane >> 4;      // 0..3 k-group

    // ---- B prologue: whole K=256 x 32-col wave stripe into registers ----
    bf16x8 bfr[8][2];
    {
        const float* bp = Bm + (size_t)(kg * 8) * Nc + blockCol + wc * 32 + l16;
#pragma unroll
        for (int ks = 0; ks < 8; ++ks) {
#pragma unroll
            for (int jf = 0; jf < 2; ++jf) {
                bf16x8 bv;
#pragma unroll
                for (int jj = 0; jj < 8; ++jj) {
                    float f = bp[(size_t)(ks * 32 + jj) * Nc + jf * 16];
                    bv[jj] = (short)f2bf(f);
                }
                bfr[ks][jf] = bv;
            }
        }
    }

    // ---- A staging addressing ----
    const int arow  = t >> 1;        // 0..127
    const int ahalf = t & 1;         // 16-float half of the 32-k slice
    const bool avalid = (blockRow + arow) < Rrows;
    const float* aptr = A + (size_t)(blockRow + arow) * 256 + ahalf * 16;
    unsigned short* wp = &As[arow * 40 + ahalf * 16];

    f32x4 acc[4][2] = {};

    const int arbase = wr * 64 + l16;

#pragma unroll
    for (int ks = 0; ks < 8; ++ks) {
        float4 g0, g1, g2, g3;
        if (avalid) {
            const float* p = aptr + ks * 32;
            g0 = *(const float4*)(p + 0);
            g1 = *(const float4*)(p + 4);
            g2 = *(const float4*)(p + 8);
            g3 = *(const float4*)(p + 12);
        } else {
            g0 = g1 = g2 = g3 = make_float4(0.f, 0.f, 0.f, 0.f);
        }
        __syncthreads();   // previous step's frag reads complete
        *(bf16x8*)(wp + 0) = pack8(g0, g1);
        *(bf16x8*)(wp + 8) = pack8(g2, g3);
        __syncthreads();   // tile visible
#pragma unroll
        for (int i = 0; i < 4; ++i) {
            bf16x8 af = *(const bf16x8*)&As[(arbase + i * 16) * 40 + kg * 8];
            acc[i][0] = __builtin_amdgcn_mfma_f32_16x16x32_bf16(af, bfr[ks][0], acc[i][0], 0, 0, 0);
            acc[i][1] = __builtin_amdgcn_mfma_f32_16x16x32_bf16(af, bfr[ks][1], acc[i][1], 0, 0, 0);
        }
    }

    // ---- epilogue: bias + store (C/D: col=lane&15, row=(lane>>4)*4+reg) ----
#pragma unroll
    for (int jf = 0; jf < 2; ++jf) {
        const int col = blockCol + wc * 32 + jf * 16 + l16;
        const float bcol = bias[col];
#pragma unroll
        for (int i = 0; i < 4; ++i) {
            const int rbase = blockRow + wr * 64 + i * 16 + kg * 4;
#pragma unroll
            for (int r = 0; r < 4; ++r) {
                const int row = rbase + r;
                if (row < Rrows)
                    Cm[(size_t)row * Nc + col] = acc[i][jf][r] + bcol;
            }
        }
    }
}

// ---------------------------------------------------------------------------
// Softmax over groups of 16 contiguous floats (per n,q,m) — in place.
// ---------------------------------------------------------------------------
__global__ __launch_bounds__(256) void softmax16_kernel(float* __restrict__ aw)
{
    int g = blockIdx.x * 256 + threadIdx.x;
    if (g >= NGRP) return;
    float4* p = (float4*)(aw + (size_t)g * 16);
    float4 v0 = p[0], v1 = p[1], v2 = p[2], v3 = p[3];
    float vals[16] = { v0.x, v0.y, v0.z, v0.w, v1.x, v1.y, v1.z, v1.w,
                       v2.x, v2.y, v2.z, v2.w, v3.x, v3.y, v3.z, v3.w };
    float mx = vals[0];
#pragma unroll
    for (int i = 1; i < 16; ++i) mx = fmaxf(mx, vals[i]);
    float s = 0.f;
#pragma unroll
    for (int i = 0; i < 16; ++i) { vals[i] = expf(vals[i] - mx); s += vals[i]; }
    float inv = 1.f / s;
#pragma unroll
    for (int i = 0; i < 16; ++i) vals[i] *= inv;
    p[0] = make_float4(vals[0], vals[1], vals[2], vals[3]);
    p[1] = make_float4(vals[4], vals[5], vals[6], vals[7]);
    p[2] = make_float4(vals[8], vals[9], vals[10], vals[11]);
    p[3] = make_float4(vals[12], vals[13], vals[14], vals[15]);
}

// ---------------------------------------------------------------------------
// Bilinear sampling + attention-weighted accumulation — float4 / 8-lane groups.
// (unchanged from R4 — 162 us, 40% HBM, next round's target)
// ---------------------------------------------------------------------------
__global__ __launch_bounds__(256) void sample_kernel(
    const float* __restrict__ value, const float* __restrict__ off,
    const float* __restrict__ aw, const float* __restrict__ refp,
    const int* __restrict__ shapes, const int* __restrict__ starts,
    float* __restrict__ samp)
{
    const int grp = blockIdx.x * 32 + (threadIdx.x >> 3);   // grid exact
    const int l8  = threadIdx.x & 7;
    const int m   = grp & (MH - 1);
    const int row = grp >> 3;             // n*LQ + q
    const int n   = row / LQ;

    const float4 offv = *(const float4*)(off + (size_t)row * 256 + m * 32 + l8 * 4);
    const float2 aw2  = *(const float2*)(aw  + (size_t)row * 128 + m * 16 + l8 * 2);

    const int lvl = l8 >> 1;
    const int H  = shapes[2 * lvl];
    const int W  = shapes[2 * lvl + 1];
    const int st = starts[lvl];
    const float rx = refp[(size_t)row * 8 + lvl * 2 + 0];
    const float ry = refp[(size_t)row * 8 + lvl * 2 + 1];

    int   idx[2][4];
    float wgt[2][4];
#pragma unroll
    for (int s = 0; s < 2; ++s) {
        const float ox = s ? offv.z : offv.x;
        const float oy = s ? offv.w : offv.y;
        const float wa = s ? aw2.y  : aw2.x;
        const float x = fmaf(rx, (float)W, ox) - 0.5f;
        const float y = fmaf(ry, (float)H, oy) - 0.5f;
        const float x0f = floorf(x), y0f = floorf(y);
        const float wx = x - x0f, wy = y - y0f;
        const int x0 = (int)x0f, y0 = (int)y0f;
        const int x1 = x0 + 1,   y1 = y0 + 1;
        const float vx0 = (x0 >= 0 && x0 < W) ? 1.f : 0.f;
        const float vx1 = (x1 >= 0 && x1 < W) ? 1.f : 0.f;
        const float vy0 = (y0 >= 0 && y0 < H) ? 1.f : 0.f;
        const float vy1 = (y1 >= 0 && y1 < H) ? 1.f : 0.f;
        const int xc0 = min(max(x0, 0), W - 1);
        const int xc1 = min(max(x1, 0), W - 1);
        const int rb0 = min(max(y0, 0), H - 1) * W;
        const int rb1 = min(max(y1, 0), H - 1) * W;
        idx[s][0] = st + rb0 + xc0;
        idx[s][1] = st + rb0 + xc1;
        idx[s][2] = st + rb1 + xc0;
        idx[s][3] = st + rb1 + xc1;
        wgt[s][0] = (1.f - wx) * (1.f - wy) * vx0 * vy0 * wa;
        wgt[s][1] = wx * (1.f - wy) * vx1 * vy0 * wa;
        wgt[s][2] = (1.f - wx) * wy * vx0 * vy1 * wa;
        wgt[s][3] = wx * wy * vx1 * vy1 * wa;
    }

    const float* vb = value + (size_t)n * LEN * 256 + m * 32 + l8 * 4;

    float4 acc = make_float4(0.f, 0.f, 0.f, 0.f);
#pragma unroll
    for (int j = 0; j < 16; ++j) {
        const int owner = j >> 1;
        const int s     = j & 1;
#pragma unroll
        for (int c = 0; c < 4; ++c) {
            const int   ic = __shfl(idx[s][c], owner, 8);
            const float wc = __shfl(wgt[s][c], owner, 8);
            const float4 v = *(const float4*)(vb + ((size_t)ic << 8));
            acc.x = fmaf(wc, v.x, acc.x);
            acc.y = fmaf(wc, v.y, acc.y);
            acc.z = fmaf(wc, v.z, acc.z);
            acc.w = fmaf(wc, v.w, acc.w);
        }
    }
    *(float4*)(samp + (size_t)row * 256 + m * 32 + l8 * 4) = acc;
}

// ---------------------------------------------------------------------------
extern "C" void kernel_launch(void* const* d_in, const int* in_sizes, int n_in,
                              void* d_out, int out_size, void* d_ws, size_t ws_size,
                              hipStream_t stream)
{
    const float* query  = (const float*)d_in[0];
    const float* refp   = (const float*)d_in[1];
    const float* inp    = (const float*)d_in[2];
    const int*   shapes = (const int*)d_in[3];
    const int*   starts = (const int*)d_in[4];
    const float* Wv     = (const float*)d_in[5];
    const float* bv     = (const float*)d_in[6];
    const float* W_off  = (const float*)d_in[7];
    const float* b_off  = (const float*)d_in[8];
    const float* W_attn = (const float*)d_in[9];
    const float* b_attn = (const float*)d_in[10];
    const float* Wo     = (const float*)d_in[11];
    const float* bo     = (const float*)d_in[12];
    float* out = (float*)d_out;

    float* ws    = (float*)d_ws;
    float* value = ws;                                   // RTOT*256
    float* off   = value + (size_t)RTOT * 256;           // RTOT*256
    float* aw    = off + (size_t)RTOT * 256;             // RTOT*128
    float* samp  = aw + (size_t)RTOT * 128;              // RTOT*256

    dim3 blk(256);
    const int rowTiles = (RTOT + 127) / 128;             // 416
    dim3 gFull(4, rowTiles);                             // Nc=256
    dim3 gHalf(2, rowTiles);                             // Nc=128

    // value projection
    gemm_mfma_bias<<<gFull, blk, 0, stream>>>(inp, Wv, bv, value, RTOT, 256);
    // sampling offsets
    gemm_mfma_bias<<<gFull, blk, 0, stream>>>(query, W_off, b_off, off, RTOT, 256);
    // attention logits
    gemm_mfma_bias<<<gHalf, blk, 0, stream>>>(query, W_attn, b_attn, aw, RTOT, 128);
    // softmax over L*P=16
    softmax16_kernel<<<(NGRP + 255) / 256, blk, 0, stream>>>(aw);
    // bilinear sampling + weighted sum
    sample_kernel<<<NGRP / 32, blk, 0, stream>>>(value, off, aw, refp, shapes, starts, samp);
    // output projection
    gemm_mfma_bias<<<gFull, blk, 0, stream>>>(samp, Wo, bo, out, RTOT, 256);
}

// Round 9
// 471.333 us; speedup vs baseline: 2.3887x; 1.1147x over previous
//
#include <hip/hip_runtime.h>
#include <math.h>

// Problem constants (match reference setup_inputs)
#define NB 4
#define LQ 13294
#define LEN 13294
#define CCH 256
#define MH 8
#define LL 4
#define PP 4
#define DD 32
#define RTOT (NB * LQ)        // 53176 rows
#define NGRP (RTOT * MH)      // 425408 (n,q,m) groups

typedef short bf16x8 __attribute__((ext_vector_type(8)));
typedef float f32x4  __attribute__((ext_vector_type(4)));

static __device__ __forceinline__ unsigned short f2bf(float f) {
    union { float f; unsigned int u; } v; v.f = f;
    unsigned int r = v.u + 0x7fffu + ((v.u >> 16) & 1u);   // RNE
    return (unsigned short)(r >> 16);
}
static __device__ __forceinline__ float bf2f(unsigned short u) {
    union { unsigned int u; float f; } v; v.u = ((unsigned int)u) << 16;
    return v.f;
}
static __device__ __forceinline__ bf16x8 pack8(float4 a, float4 b) {
    bf16x8 r;
    r[0] = (short)f2bf(a.x); r[1] = (short)f2bf(a.y);
    r[2] = (short)f2bf(a.z); r[3] = (short)f2bf(a.w);
    r[4] = (short)f2bf(b.x); r[5] = (short)f2bf(b.y);
    r[6] = (short)f2bf(b.z); r[7] = (short)f2bf(b.w);
    return r;
}

// ---------------------------------------------------------------------------
// One-time fp32 -> bf16 row conversion. 8 elements/thread, exact grid.
// ---------------------------------------------------------------------------
__global__ __launch_bounds__(256) void cvt_rows_kernel(
    const float* __restrict__ src, unsigned short* __restrict__ dst)
{
    const size_t i = ((size_t)blockIdx.x * 256 + threadIdx.x) * 8;
    float4 a = *(const float4*)(src + i);
    float4 b = *(const float4*)(src + i + 4);
    *(bf16x8*)(dst + i) = pack8(a, b);
}

// ---------------------------------------------------------------------------
// One-time weight transpose + convert: W (256 x Nc) fp32 -> Wt (Nc x 256) bf16.
// ---------------------------------------------------------------------------
__global__ __launch_bounds__(256) void transpose_cvt_kernel(
    const float* __restrict__ W, unsigned short* __restrict__ Wt, int Nc)
{
    const int r = blockIdx.x;      // k row, 0..255
    const int c = threadIdx.x;     // col
    if (c < Nc) Wt[(size_t)c * 256 + r] = f2bf(W[(size_t)r * Nc + c]);
}

// ---------------------------------------------------------------------------
// bf16-MFMA GEMM with bias: C[r,c] = sum_k A[r,k]*B[k,c] + bias[c]
// A: (Rrows, 256) bf16 row-major; Bt: (Nc, 256) bf16 (= B transposed). K=256.
// BM=128, BN=64, BK=32. 256 threads = 4 waves in 2x2; per-wave 64x32 out.
// Bt fragments (whole K) preloaded to registers as contiguous bf16x8 loads;
// A staged in LDS [128][40] ushort (pad 8 -> <=2-way bank conflicts, free).
// OUT_BF16: store bf16 (value path) else fp32.
// ---------------------------------------------------------------------------
template<bool OUT_BF16>
__global__ __launch_bounds__(256) void gemm_mfma_bias(
    const unsigned short* __restrict__ A, const unsigned short* __restrict__ Bt,
    const float* __restrict__ bias, void* __restrict__ Cm,
    int Rrows, int Nc)
{
    __shared__ unsigned short As[128 * 40];

    const int t    = threadIdx.x;
    const int lane = t & 63;
    const int w    = t >> 6;
    const int wr   = w >> 1;        // 0..1 : row half
    const int wc   = w & 1;         // 0..1 : col half
    const int blockRow = blockIdx.y * 128;
    const int blockCol = blockIdx.x * 64;

    const int l16 = lane & 15;
    const int kg  = lane >> 4;      // 0..3 k-octet group

    // ---- B prologue: 16 contiguous bf16x8 loads from Bt (m97 B^T pattern) ----
    bf16x8 bfr[8][2];
    {
        const unsigned short* bp =
            Bt + (size_t)(blockCol + wc * 32 + l16) * 256 + kg * 8;
#pragma unroll
        for (int ks = 0; ks < 8; ++ks) {
#pragma unroll
            for (int jf = 0; jf < 2; ++jf) {
                bfr[ks][jf] = *(const bf16x8*)(bp + (size_t)jf * 16 * 256 + ks * 32);
            }
        }
    }

    // ---- A staging addressing: 2 threads per row, 16 bf16 each ----
    const int arow  = t >> 1;        // 0..127
    const int ahalf = t & 1;         // k-half of the 32-k slice
    const bool avalid = (blockRow + arow) < Rrows;
    const unsigned short* aptr = A + (size_t)(blockRow + arow) * 256 + ahalf * 16;
    unsigned short* wp = &As[arow * 40 + ahalf * 16];

    f32x4 acc[4][2] = {};
    const int arbase = wr * 64 + l16;

#pragma unroll
    for (int ks = 0; ks < 8; ++ks) {
        bf16x8 a0, a1;
        if (avalid) {
            const unsigned short* p = aptr + ks * 32;
            a0 = *(const bf16x8*)(p + 0);
            a1 = *(const bf16x8*)(p + 8);
        } else {
            a0 = (bf16x8)(short)0; a1 = (bf16x8)(short)0;
        }
        __syncthreads();   // previous step's frag reads complete
        *(bf16x8*)(wp + 0) = a0;
        *(bf16x8*)(wp + 8) = a1;
        __syncthreads();   // tile visible
#pragma unroll
        for (int i = 0; i < 4; ++i) {
            bf16x8 af = *(const bf16x8*)&As[(arbase + i * 16) * 40 + kg * 8];
            acc[i][0] = __builtin_amdgcn_mfma_f32_16x16x32_bf16(af, bfr[ks][0], acc[i][0], 0, 0, 0);
            acc[i][1] = __builtin_amdgcn_mfma_f32_16x16x32_bf16(af, bfr[ks][1], acc[i][1], 0, 0, 0);
        }
    }

    // ---- epilogue: bias + store (C/D: col=lane&15, row=(lane>>4)*4+reg) ----
#pragma unroll
    for (int jf = 0; jf < 2; ++jf) {
        const int col = blockCol + wc * 32 + jf * 16 + l16;
        const float bcol = bias[col];
#pragma unroll
        for (int i = 0; i < 4; ++i) {
            const int rbase = blockRow + wr * 64 + i * 16 + kg * 4;
#pragma unroll
            for (int r = 0; r < 4; ++r) {
                const int row = rbase + r;
                if (row < Rrows) {
                    const float val = acc[i][jf][r] + bcol;
                    if (OUT_BF16)
                        ((unsigned short*)Cm)[(size_t)row * Nc + col] = f2bf(val);
                    else
                        ((float*)Cm)[(size_t)row * Nc + col] = val;
                }
            }
        }
    }
}

// ---------------------------------------------------------------------------
// Softmax over groups of 16 contiguous floats (per n,q,m) — in place.
// ---------------------------------------------------------------------------
__global__ __launch_bounds__(256) void softmax16_kernel(float* __restrict__ aw)
{
    int g = blockIdx.x * 256 + threadIdx.x;
    if (g >= NGRP) return;
    float4* p = (float4*)(aw + (size_t)g * 16);
    float4 v0 = p[0], v1 = p[1], v2 = p[2], v3 = p[3];
    float vals[16] = { v0.x, v0.y, v0.z, v0.w, v1.x, v1.y, v1.z, v1.w,
                       v2.x, v2.y, v2.z, v2.w, v3.x, v3.y, v3.z, v3.w };
    float mx = vals[0];
#pragma unroll
    for (int i = 1; i < 16; ++i) mx = fmaxf(mx, vals[i]);
    float s = 0.f;
#pragma unroll
    for (int i = 0; i < 16; ++i) { vals[i] = expf(vals[i] - mx); s += vals[i]; }
    float inv = 1.f / s;
#pragma unroll
    for (int i = 0; i < 16; ++i) vals[i] *= inv;
    p[0] = make_float4(vals[0], vals[1], vals[2], vals[3]);
    p[1] = make_float4(vals[4], vals[5], vals[6], vals[7]);
    p[2] = make_float4(vals[8], vals[9], vals[10], vals[11]);
    p[3] = make_float4(vals[12], vals[13], vals[14], vals[15]);
}

// ---------------------------------------------------------------------------
// Bilinear sampling + weighted accumulation — bf16 value gathers (8B/corner),
// 8-lane groups, branchless, owner-lane coordinate math + __shfl broadcast.
// value: (N*LEN, 256) bf16;  samp out: (N*LQ, 256) bf16.
// off (fp32), aw (fp32), refp (fp32) unchanged.
// ---------------------------------------------------------------------------
__global__ __launch_bounds__(256) void sample_kernel(
    const unsigned short* __restrict__ value, const float* __restrict__ off,
    const float* __restrict__ aw, const float* __restrict__ refp,
    const int* __restrict__ shapes, const int* __restrict__ starts,
    unsigned short* __restrict__ samp)
{
    const int grp = blockIdx.x * 32 + (threadIdx.x >> 3);   // grid exact
    const int l8  = threadIdx.x & 7;
    const int m   = grp & (MH - 1);
    const int row = grp >> 3;             // n*LQ + q
    const int n   = row / LQ;

    const float4 offv = *(const float4*)(off + (size_t)row * 256 + m * 32 + l8 * 4);
    const float2 aw2  = *(const float2*)(aw  + (size_t)row * 128 + m * 16 + l8 * 2);

    const int lvl = l8 >> 1;
    const int H  = shapes[2 * lvl];
    const int W  = shapes[2 * lvl + 1];
    const int st = starts[lvl];
    const float rx = refp[(size_t)row * 8 + lvl * 2 + 0];
    const float ry = refp[(size_t)row * 8 + lvl * 2 + 1];

    int   idx[2][4];
    float wgt[2][4];
#pragma unroll
    for (int s = 0; s < 2; ++s) {
        const float ox = s ? offv.z : offv.x;
        const float oy = s ? offv.w : offv.y;
        const float wa = s ? aw2.y  : aw2.x;
        const float x = fmaf(rx, (float)W, ox) - 0.5f;
        const float y = fmaf(ry, (float)H, oy) - 0.5f;
        const float x0f = floorf(x), y0f = floorf(y);
        const float wx = x - x0f, wy = y - y0f;
        const int x0 = (int)x0f, y0 = (int)y0f;
        const int x1 = x0 + 1,   y1 = y0 + 1;
        const float vx0 = (x0 >= 0 && x0 < W) ? 1.f : 0.f;
        const float vx1 = (x1 >= 0 && x1 < W) ? 1.f : 0.f;
        const float vy0 = (y0 >= 0 && y0 < H) ? 1.f : 0.f;
        const float vy1 = (y1 >= 0 && y1 < H) ? 1.f : 0.f;
        const int xc0 = min(max(x0, 0), W - 1);
        const int xc1 = min(max(x1, 0), W - 1);
        const int rb0 = min(max(y0, 0), H - 1) * W;
        const int rb1 = min(max(y1, 0), H - 1) * W;
        idx[s][0] = st + rb0 + xc0;
        idx[s][1] = st + rb0 + xc1;
        idx[s][2] = st + rb1 + xc0;
        idx[s][3] = st + rb1 + xc1;
        wgt[s][0] = (1.f - wx) * (1.f - wy) * vx0 * vy0 * wa;
        wgt[s][1] = wx * (1.f - wy) * vx1 * vy0 * wa;
        wgt[s][2] = (1.f - wx) * wy * vx0 * vy1 * wa;
        wgt[s][3] = wx * wy * vx1 * vy1 * wa;
    }

    const unsigned short* vb = value + (size_t)n * LEN * 256 + m * 32 + l8 * 4;

    float acx = 0.f, acy = 0.f, acz = 0.f, acw = 0.f;
#pragma unroll
    for (int j = 0; j < 16; ++j) {
        const int owner = j >> 1;
        const int s     = j & 1;
#pragma unroll
        for (int c = 0; c < 4; ++c) {
            const int   ic = __shfl(idx[s][c], owner, 8);
            const float wc = __shfl(wgt[s][c], owner, 8);
            const ushort4 v = *(const ushort4*)(vb + ((size_t)ic << 8));
            acx = fmaf(wc, bf2f(v.x), acx);
            acy = fmaf(wc, bf2f(v.y), acy);
            acz = fmaf(wc, bf2f(v.z), acz);
            acw = fmaf(wc, bf2f(v.w), acw);
        }
    }
    ushort4 o;
    o.x = f2bf(acx); o.y = f2bf(acy); o.z = f2bf(acz); o.w = f2bf(acw);
    *(ushort4*)(samp + (size_t)row * 256 + m * 32 + l8 * 4) = o;
}

// ---------------------------------------------------------------------------
extern "C" void kernel_launch(void* const* d_in, const int* in_sizes, int n_in,
                              void* d_out, int out_size, void* d_ws, size_t ws_size,
                              hipStream_t stream)
{
    const float* query  = (const float*)d_in[0];
    const float* refp   = (const float*)d_in[1];
    const float* inp    = (const float*)d_in[2];
    const int*   shapes = (const int*)d_in[3];
    const int*   starts = (const int*)d_in[4];
    const float* Wv     = (const float*)d_in[5];
    const float* bv     = (const float*)d_in[6];
    const float* W_off  = (const float*)d_in[7];
    const float* b_off  = (const float*)d_in[8];
    const float* W_attn = (const float*)d_in[9];
    const float* b_attn = (const float*)d_in[10];
    const float* Wo     = (const float*)d_in[11];
    const float* bo     = (const float*)d_in[12];
    float* out = (float*)d_out;

    // Workspace layout (163.8 MB < 190 MB known-available):
    float* off = (float*)d_ws;                               // RTOT*256 f32
    float* aw  = off + (size_t)RTOT * 256;                   // RTOT*128 f32
    unsigned short* value_bf = (unsigned short*)(aw + (size_t)RTOT * 128); // RTOT*256
    unsigned short* query_bf = value_bf + (size_t)RTOT * 256;              // RTOT*256
    unsigned short* inp_bf   = query_bf + (size_t)RTOT * 256;              // RTOT*256
    unsigned short* samp_bf  = inp_bf;   // alias: inp_bf dead after value-GEMM
    unsigned short* Wv_t     = inp_bf + (size_t)RTOT * 256;  // 256*256
    unsigned short* Woff_t   = Wv_t + 256 * 256;             // 256*256
    unsigned short* Wattn_t  = Woff_t + 256 * 256;           // 128*256
    unsigned short* Wo_t     = Wattn_t + 128 * 256;          // 256*256

    dim3 blk(256);
    const int cvtBlocks = (int)(((size_t)RTOT * 256) / (256 * 8));  // 6647 exact
    const int rowTiles = (RTOT + 127) / 128;             // 416
    dim3 gFull(4, rowTiles);                             // Nc=256
    dim3 gHalf(2, rowTiles);                             // Nc=128

    // one-time conversions
    cvt_rows_kernel<<<cvtBlocks, blk, 0, stream>>>(inp, inp_bf);
    cvt_rows_kernel<<<cvtBlocks, blk, 0, stream>>>(query, query_bf);
    transpose_cvt_kernel<<<256, blk, 0, stream>>>(Wv, Wv_t, 256);
    transpose_cvt_kernel<<<256, blk, 0, stream>>>(W_off, Woff_t, 256);
    transpose_cvt_kernel<<<256, blk, 0, stream>>>(W_attn, Wattn_t, 128);
    transpose_cvt_kernel<<<256, blk, 0, stream>>>(Wo, Wo_t, 256);

    // value projection (bf16 out, feeds gathers)
    gemm_mfma_bias<true><<<gFull, blk, 0, stream>>>(inp_bf, Wv_t, bv, value_bf, RTOT, 256);
    // sampling offsets (fp32 out — coordinates must stay fp32)
    gemm_mfma_bias<false><<<gFull, blk, 0, stream>>>(query_bf, Woff_t, b_off, off, RTOT, 256);
    // attention logits (fp32 out)
    gemm_mfma_bias<false><<<gHalf, blk, 0, stream>>>(query_bf, Wattn_t, b_attn, aw, RTOT, 128);
    // softmax over L*P=16
    softmax16_kernel<<<(NGRP + 255) / 256, blk, 0, stream>>>(aw);
    // bilinear sampling + weighted sum (bf16 gathers, bf16 samp out)
    sample_kernel<<<NGRP / 32, blk, 0, stream>>>(value_bf, off, aw, refp, shapes, starts, samp_bf);
    // output projection (fp32 out)
    gemm_mfma_bias<false><<<gFull, blk, 0, stream>>>(samp_bf, Wo_t, bo, out, RTOT, 256);
}